// Round 2
// baseline (367.916 us; speedup 1.0000x reference)
//
#include <hip/hip_runtime.h>
#include <stdint.h>

#define NB 2
#define NH 12
#define NS 2048
#define ND 64

typedef __attribute__((ext_vector_type(4))) float f32x4;
typedef __attribute__((ext_vector_type(8))) short s16x8;
typedef __attribute__((ext_vector_type(4))) uint32_t u32x4;

__device__ __forceinline__ short f2bf(float x) {
    return __builtin_bit_cast(short, (__bf16)x);
}
__device__ __forceinline__ float bf2f(short h) {
    uint32_t u = ((uint32_t)(unsigned short)h) << 16;
    return __builtin_bit_cast(float, u);
}
__device__ __forceinline__ f32x4 mfma16(s16x8 a, s16x8 b, f32x4 c) {
    return __builtin_amdgcn_mfma_f32_16x16x32_bf16(a, b, c, 0, 0, 0);
}

// ---------- pre-pass 1: mask int32 -> bitmask (1 bit / element), 1 MB ----------
__global__ void kbits(const int* __restrict__ maskg, uint32_t* __restrict__ bits) {
    int wi = blockIdx.x * 256 + threadIdx.x;  // word index
    const int* mp = maskg + (size_t)wi * 32;
    uint32_t v = 0;
#pragma unroll
    for (int i = 0; i < 8; i++) {
        int4 q = *(const int4*)(mp + i * 4);
        v |= ((uint32_t)(q.x != 0) << (i * 4)) | ((uint32_t)(q.y != 0) << (i * 4 + 1)) |
             ((uint32_t)(q.z != 0) << (i * 4 + 2)) | ((uint32_t)(q.w != 0) << (i * 4 + 3));
    }
    bits[wi] = v;
}

// ---------- pre-pass 2: VwT[b,h,d,k] = V[b,h,k,d]*w[k] as bf16, 6.3 MB ----------
__global__ void kvwt(const float* __restrict__ Vg, const float* __restrict__ wg,
                     unsigned short* __restrict__ vwt) {
    __shared__ float tile[32][65];
    int blk = blockIdx.x;
    int bh = blk >> 6;
    int k0 = (blk & 63) * 32;
    const float* Vh = Vg + ((size_t)bh * NS + k0) * ND;
    int t = threadIdx.x;
    {
        int kk = t >> 3, c = (t & 7) * 8;
        f32x4 a = *(const f32x4*)(Vh + kk * ND + c);
        f32x4 b4 = *(const f32x4*)(Vh + kk * ND + c + 4);
        float wk = wg[k0 + kk];
#pragma unroll
        for (int j = 0; j < 4; j++) {
            tile[kk][c + j] = a[j] * wk;
            tile[kk][c + 4 + j] = b4[j] * wk;
        }
    }
    __syncthreads();
    {
        int d = t >> 2, kb2 = (t & 3) * 8;
        s16x8 o;
#pragma unroll
        for (int j = 0; j < 8; j++) o[j] = f2bf(tile[kb2 + j][d]);
        *(s16x8*)(vwt + ((size_t)bh * ND + d) * NS + k0 + kb2) = o;
    }
}

// ---------- main fused kernel ----------
// One WG = one (b,h) x 32 query rows. 8 waves. P lives entirely in REGISTERS
// (uint32 preg[16][2][2] = 64 VGPRs of packed bf16). Each wave owns k-slices
// {kc*128 + wv*16 .. +16}. Phase 2 (p_attn stream) + phase 3 (partial PV with
// register-P as MFMA B operand, custom k-slot mapping) are fused; 8-way LDS
// reduction of partial out at the end. LDS = 69.6 KB partials (+68-float row
// pitch to avoid bank conflicts) -> 2 WGs/CU, 16 waves/CU.
template <bool WS>
__global__ __launch_bounds__(512, 4) void attn_main(
    const float* __restrict__ Qg, const float* __restrict__ Kg,
    const float* __restrict__ Vg, const int* __restrict__ maskg,
    const float* __restrict__ wg, const uint32_t* __restrict__ bitsg,
    const unsigned short* __restrict__ vwtg, float* __restrict__ outg,
    float* __restrict__ pg) {
    extern __shared__ char smem[];
    constexpr int PO_PITCH = 68;                       // floats per q-row (pad 64->68)
    float* pO = (float*)smem;                          // [8][32][68] = 69632 B
    float* red = (float*)(smem + 8 * 32 * PO_PITCH * 4);  // [8][32]
    float* rinv_sh = red + 8 * 32;                     // [32]

    int bid = blockIdx.x;
    // XCD-aware swizzle (nwg=1536 % 8 == 0 -> bijective)
    int swz = (bid & 7) * (1536 / 8) + (bid >> 3);
    int bh = swz >> 6;
    int qt = swz & 63;
    int b = bh / NH;
    int q0 = qt * 32;

    const float* Qh = Qg + (size_t)bh * NS * ND;
    const float* Kh = Kg + (size_t)bh * NS * ND;
    const float* Vh = Vg + (size_t)bh * NS * ND;
    float* outh = outg + (size_t)bh * NS * ND;
    float* ph = pg + ((size_t)bh * NS + q0) * NS;
    const int* maskb = maskg + (size_t)b * NS * NS;
    const uint32_t* bitsb = bitsg + (size_t)b * (NS * (NS / 32));

    int tid = threadIdx.x;
    int wv = tid >> 6, lane = tid & 63;
    int m = lane & 15, kb = lane >> 4;

    // Q fragments (B operand of QK^T), 1/sqrt(64) folded in
    s16x8 qf[2][2];
#pragma unroll
    for (int n = 0; n < 2; n++)
#pragma unroll
        for (int ks = 0; ks < 2; ks++) {
            const float* src = Qh + (size_t)(q0 + n * 16 + m) * ND + ks * 32 + kb * 8;
            f32x4 a = *(const f32x4*)src;
            f32x4 c4 = *(const f32x4*)(src + 4);
            s16x8 f;
#pragma unroll
            for (int j = 0; j < 4; j++) {
                f[j] = f2bf(a[j] * 0.125f);
                f[4 + j] = f2bf(c4[j] * 0.125f);
            }
            qf[n][ks] = f;
        }

    // ---- Phase 1: scores = (K Q^T)/8, mask, relu -> preg (registers), ssum ----
    uint32_t preg[16][2][2];
    float ssum[2] = {0.f, 0.f};
#pragma unroll
    for (int kc = 0; kc < 16; kc++) {
        int k0 = kc * 128;
        int krow = k0 + wv * 16;
        s16x8 kf[2];
#pragma unroll
        for (int ks = 0; ks < 2; ks++) {
            const float* src = Kh + (size_t)(krow + m) * ND + ks * 32 + kb * 8;
            f32x4 a = *(const f32x4*)src;
            f32x4 c4 = *(const f32x4*)(src + 4);
            s16x8 f;
#pragma unroll
            for (int j = 0; j < 4; j++) {
                f[j] = f2bf(a[j]);
                f[4 + j] = f2bf(c4[j]);
            }
            kf[ks] = f;
        }
        f32x4 c0 = {0.f, 0.f, 0.f, 0.f}, c1 = {0.f, 0.f, 0.f, 0.f};
        c0 = mfma16(kf[0], qf[0][0], c0);
        c0 = mfma16(kf[1], qf[0][1], c0);
        c1 = mfma16(kf[0], qf[1][0], c1);
        c1 = mfma16(kf[1], qf[1][1], c1);

        int kcol = krow + kb * 4;  // 4 consecutive score columns per lane
#pragma unroll
        for (int n = 0; n < 2; n++) {
            f32x4 c = n ? c1 : c0;
            int qglob = q0 + n * 16 + m;
            uint32_t keepbits;
            if (WS) {
                uint32_t word = bitsb[(size_t)qglob * (NS / 32) + (kcol >> 5)];
                keepbits = word >> (kcol & 31);
            } else {
                const int4 mi = *(const int4*)(maskb + (size_t)qglob * NS + kcol);
                keepbits = (uint32_t)(mi.x != 0) | ((uint32_t)(mi.y != 0) << 1) |
                           ((uint32_t)(mi.z != 0) << 2) | ((uint32_t)(mi.w != 0) << 3);
            }
            float p[4];
#pragma unroll
            for (int r = 0; r < 4; r++) {
                float s = c[r];
                bool keep = ((keepbits >> r) & 1u) && (s > 0.f);
                p[r] = keep ? s : 0.f;
            }
            ssum[n] += p[0] * p[0] + p[1] * p[1] + p[2] * p[2] + p[3] * p[3];
            preg[kc][n][0] = (uint32_t)(unsigned short)f2bf(p[0]) |
                             ((uint32_t)(unsigned short)f2bf(p[1]) << 16);
            preg[kc][n][1] = (uint32_t)(unsigned short)f2bf(p[2]) |
                             ((uint32_t)(unsigned short)f2bf(p[3]) << 16);
        }
    }

    // ---- row reduction -> 1/rms ----
    ssum[0] += __shfl_xor(ssum[0], 16);
    ssum[0] += __shfl_xor(ssum[0], 32);
    ssum[1] += __shfl_xor(ssum[1], 16);
    ssum[1] += __shfl_xor(ssum[1], 32);
    if (lane < 16) {
        red[wv * 32 + lane] = ssum[0];
        red[wv * 32 + 16 + lane] = ssum[1];
    }
    __syncthreads();
    if (tid < 32) {
        float s = 0.f;
#pragma unroll
        for (int i = 0; i < 8; i++) s += red[i * 32 + tid];
        rinv_sh[tid] = 1.0f / sqrtf(s * (1.0f / NS) + 1e-6f);
    }
    __syncthreads();

    // ---- Fused Phase 2+3: stream p_attn from regs + partial PV per wave ----
    f32x4 acc[4][2];
#pragma unroll
    for (int dt = 0; dt < 4; dt++)
#pragma unroll
        for (int n = 0; n < 2; n++) acc[dt][n] = (f32x4){0.f, 0.f, 0.f, 0.f};

#pragma unroll
    for (int t = 0; t < 8; t++) {
        const int kc0 = 2 * t, kc1 = 2 * t + 1;
        // p_attn stores straight from registers
#pragma unroll
        for (int n = 0; n < 2; n++) {
            int q = n * 16 + m;
            float ri = rinv_sh[q];
#pragma unroll
            for (int h = 0; h < 2; h++) {
                const int kcA = 2 * t + h;
                int kcol = kcA * 128 + wv * 16 + kb * 4;
                f32x4 w4 = *(const f32x4*)(wg + kcol);
                uint32_t lo = preg[kcA][n][0], hi = preg[kcA][n][1];
                f32x4 o;
                o[0] = bf2f((short)(lo & 0xffff)) * w4[0] * ri;
                o[1] = bf2f((short)(lo >> 16)) * w4[1] * ri;
                o[2] = bf2f((short)(hi & 0xffff)) * w4[2] * ri;
                o[3] = bf2f((short)(hi >> 16)) * w4[3] * ri;
                *(f32x4*)(ph + (size_t)q * NS + kcol) = o;
            }
        }
        // A fragments: VwT[d][k] at the same custom k-slot mapping as preg
        s16x8 afr[4];
#pragma unroll
        for (int dt = 0; dt < 4; dt++) {
            if (WS) {
                const unsigned short* rb =
                    vwtg + ((size_t)bh * ND + dt * 16 + m) * NS + wv * 16 + kb * 4;
                uint2 l0 = *(const uint2*)(rb + kc0 * 128);
                uint2 l1 = *(const uint2*)(rb + kc1 * 128);
                u32x4 uu = {l0.x, l0.y, l1.x, l1.y};
                afr[dt] = __builtin_bit_cast(s16x8, uu);
            } else {
                s16x8 a;
#pragma unroll
                for (int j = 0; j < 4; j++) {
                    int k1 = kc0 * 128 + wv * 16 + kb * 4 + j;
                    int k2 = kc1 * 128 + wv * 16 + kb * 4 + j;
                    a[j] = f2bf(Vh[(size_t)k1 * ND + dt * 16 + m] * wg[k1]);
                    a[4 + j] = f2bf(Vh[(size_t)k2 * ND + dt * 16 + m] * wg[k2]);
                }
                afr[dt] = a;
            }
        }
#pragma unroll
        for (int n = 0; n < 2; n++) {
            u32x4 uu = {preg[kc0][n][0], preg[kc0][n][1], preg[kc1][n][0], preg[kc1][n][1]};
            s16x8 bfr = __builtin_bit_cast(s16x8, uu);
#pragma unroll
            for (int dt = 0; dt < 4; dt++) acc[dt][n] = mfma16(afr[dt], bfr, acc[dt][n]);
        }
    }

    // ---- per-wave partials -> LDS -> 8-way reduce -> out ----
#pragma unroll
    for (int dt = 0; dt < 4; dt++)
#pragma unroll
        for (int n = 0; n < 2; n++) {
            int q = n * 16 + m;
            *(f32x4*)(pO + ((size_t)wv * 32 + q) * PO_PITCH + dt * 16 + kb * 4) = acc[dt][n];
        }
    __syncthreads();
    {
        int q = tid >> 4, dg = (tid & 15) * 4;
        f32x4 s = {0.f, 0.f, 0.f, 0.f};
#pragma unroll
        for (int v = 0; v < 8; v++) {
            f32x4 x = *(const f32x4*)(pO + ((size_t)v * 32 + q) * PO_PITCH + dg);
            s[0] += x[0];
            s[1] += x[1];
            s[2] += x[2];
            s[3] += x[3];
        }
        float ri = rinv_sh[q];
        f32x4 o = {s[0] * ri, s[1] * ri, s[2] * ri, s[3] * ri};
        *(f32x4*)(outh + (size_t)(q0 + q) * ND + dg) = o;
    }
}

extern "C" void kernel_launch(void* const* d_in, const int* in_sizes, int n_in,
                              void* d_out, int out_size, void* d_ws, size_t ws_size,
                              hipStream_t stream) {
    const float* Q = (const float*)d_in[0];
    const float* K = (const float*)d_in[1];
    const float* V = (const float*)d_in[2];
    const int* mask = (const int*)d_in[3];
    const float* w = (const float*)d_in[4];
    float* out = (float*)d_out;
    float* pattn = out + (size_t)NB * NH * NS * ND;

    const size_t bits_bytes = (size_t)NB * NS * (NS / 32) * sizeof(uint32_t);     // 1 MB
    const size_t vwt_bytes = (size_t)NB * NH * ND * NS * sizeof(unsigned short);  // 6.3 MB
    const int nwg = NB * NH * (NS / 32);  // 1536
    const int smem = 8 * 32 * 68 * 4 + 8 * 32 * 4 + 32 * 4;  // 70784 B

    if (ws_size >= bits_bytes + vwt_bytes) {
        uint32_t* bits = (uint32_t*)d_ws;
        unsigned short* vwt = (unsigned short*)((char*)d_ws + bits_bytes);
        kbits<<<(NB * NS * NS / 32) / 256, 256, 0, stream>>>(mask, bits);
        kvwt<<<NB * NH * (NS / 32), 256, 0, stream>>>(V, w, vwt);
        hipFuncSetAttribute(reinterpret_cast<const void*>(&attn_main<true>),
                            hipFuncAttributeMaxDynamicSharedMemorySize, smem);
        attn_main<true><<<nwg, 512, smem, stream>>>(Q, K, V, mask, w, bits, vwt, out, pattn);
    } else {
        hipFuncSetAttribute(reinterpret_cast<const void*>(&attn_main<false>),
                            hipFuncAttributeMaxDynamicSharedMemorySize, smem);
        attn_main<false><<<nwg, 512, smem, stream>>>(Q, K, V, mask, w, nullptr, nullptr, out,
                                                     pattn);
    }
}

// Round 3
// 309.634 us; speedup vs baseline: 1.1882x; 1.1882x over previous
//
#include <hip/hip_runtime.h>
#include <stdint.h>

#define NB 2
#define NH 12
#define NS 2048
#define ND 64

typedef __attribute__((ext_vector_type(4))) float f32x4;
typedef __attribute__((ext_vector_type(8))) short s16x8;
typedef __attribute__((ext_vector_type(4))) uint32_t u32x4;

__device__ __forceinline__ short f2bf(float x) {
    return __builtin_bit_cast(short, (__bf16)x);
}
__device__ __forceinline__ float bf2f(short h) {
    uint32_t u = ((uint32_t)(unsigned short)h) << 16;
    return __builtin_bit_cast(float, u);
}
__device__ __forceinline__ f32x4 mfma16(s16x8 a, s16x8 b, f32x4 c) {
    return __builtin_amdgcn_mfma_f32_16x16x32_bf16(a, b, c, 0, 0, 0);
}

// ---------- pre-pass 1: mask int32 -> bitmask (1 bit / element), 1 MB ----------
__global__ void kbits(const int* __restrict__ maskg, uint32_t* __restrict__ bits) {
    int wi = blockIdx.x * 256 + threadIdx.x;  // word index
    const int* mp = maskg + (size_t)wi * 32;
    uint32_t v = 0;
#pragma unroll
    for (int i = 0; i < 8; i++) {
        int4 q = *(const int4*)(mp + i * 4);
        v |= ((uint32_t)(q.x != 0) << (i * 4)) | ((uint32_t)(q.y != 0) << (i * 4 + 1)) |
             ((uint32_t)(q.z != 0) << (i * 4 + 2)) | ((uint32_t)(q.w != 0) << (i * 4 + 3));
    }
    bits[wi] = v;
}

// ---------- pre-pass 2: VwT[b,h,d,k] = V[b,h,k,d]*w[k] as bf16, 6.3 MB ----------
__global__ void kvwt(const float* __restrict__ Vg, const float* __restrict__ wg,
                     unsigned short* __restrict__ vwt) {
    __shared__ float tile[32][65];
    int blk = blockIdx.x;
    int bh = blk >> 6;
    int k0 = (blk & 63) * 32;
    const float* Vh = Vg + ((size_t)bh * NS + k0) * ND;
    int t = threadIdx.x;
    {
        int kk = t >> 3, c = (t & 7) * 8;
        f32x4 a = *(const f32x4*)(Vh + kk * ND + c);
        f32x4 b4 = *(const f32x4*)(Vh + kk * ND + c + 4);
        float wk = wg[k0 + kk];
#pragma unroll
        for (int j = 0; j < 4; j++) {
            tile[kk][c + j] = a[j] * wk;
            tile[kk][c + 4 + j] = b4[j] * wk;
        }
    }
    __syncthreads();
    {
        int d = t >> 2, kb2 = (t & 3) * 8;
        s16x8 o;
#pragma unroll
        for (int j = 0; j < 8; j++) o[j] = f2bf(tile[kb2 + j][d]);
        *(s16x8*)(vwt + ((size_t)bh * ND + d) * NS + k0 + kb2) = o;
    }
}

// ---------- pre-pass 3: K f32 -> bf16 row-major copy, 6.3 MB ----------
__global__ void kcast(const float* __restrict__ in, unsigned short* __restrict__ outp) {
    size_t t = (size_t)blockIdx.x * 256 + threadIdx.x;
    const float* p = in + t * 8;
    f32x4 a = *(const f32x4*)p;
    f32x4 b = *(const f32x4*)(p + 4);
    s16x8 o;
#pragma unroll
    for (int j = 0; j < 4; j++) {
        o[j] = f2bf(a[j]);
        o[4 + j] = f2bf(b[j]);
    }
    *(s16x8*)(outp + t * 8) = o;
}

// ---------- main fused kernel ----------
// One WG = one (b,h) x 32 query rows, 8 waves. P in registers (preg[16][2][2]).
// Fused loop per t (2 k-chunks): stage bf16 P -> LDS tile [32][256] (XOR
// (q&7)<<4) -> coalesced fp32 p_attn stream (512B/row segments, nontemporal)
// + partial PV MFMA from registers. Out reduced cross-wave in two d-halves
// through a [8][32][36] fp32 buffer aliased over the staging tile.
// LDS total 38016 B.
template <bool WS>
__global__ __launch_bounds__(512, 4) void attn_main(
    const float* __restrict__ Qg, const float* __restrict__ Kg,
    const float* __restrict__ Vg, const int* __restrict__ maskg,
    const float* __restrict__ wg, const uint32_t* __restrict__ bitsg,
    const unsigned short* __restrict__ vwtg, const unsigned short* __restrict__ kbfg,
    float* __restrict__ outg, float* __restrict__ pg) {
    extern __shared__ char smem[];
    char* stage = smem;                      // [32 rows][512 B] bf16, 16384 B (aliases pO)
    float* pO = (float*)smem;                // [8][32][36] fp32, 36864 B
    float* red = (float*)(smem + 36864);     // [8][32]
    float* rinv_sh = red + 256;              // [32]

    int bid = blockIdx.x;
    // XCD-aware swizzle (nwg=1536 % 8 == 0 -> bijective)
    int swz = (bid & 7) * (1536 / 8) + (bid >> 3);
    int bh = swz >> 6;
    int qt = swz & 63;
    int b = bh / NH;
    int q0 = qt * 32;

    const float* Qh = Qg + (size_t)bh * NS * ND;
    const float* Kh = Kg + (size_t)bh * NS * ND;
    const float* Vh = Vg + (size_t)bh * NS * ND;
    const unsigned short* kbfh = WS ? kbfg + (size_t)bh * NS * ND : nullptr;
    float* outh = outg + (size_t)bh * NS * ND;
    float* ph = pg + ((size_t)bh * NS + q0) * NS;
    const int* maskb = maskg + (size_t)b * NS * NS;
    const uint32_t* bitsb = bitsg + (size_t)b * (NS * (NS / 32));

    int tid = threadIdx.x;
    int wv = tid >> 6, lane = tid & 63;
    int m = lane & 15, kb = lane >> 4;

    // Q fragments (B operand of QK^T), 1/sqrt(64) folded in
    s16x8 qf[2][2];
#pragma unroll
    for (int n = 0; n < 2; n++)
#pragma unroll
        for (int ks = 0; ks < 2; ks++) {
            const float* src = Qh + (size_t)(q0 + n * 16 + m) * ND + ks * 32 + kb * 8;
            f32x4 a = *(const f32x4*)src;
            f32x4 c4 = *(const f32x4*)(src + 4);
            s16x8 f;
#pragma unroll
            for (int j = 0; j < 4; j++) {
                f[j] = f2bf(a[j] * 0.125f);
                f[4 + j] = f2bf(c4[j] * 0.125f);
            }
            qf[n][ks] = f;
        }

    // ---- Phase 1: scores = (K Q^T)/8, mask, relu -> preg (registers), ssum ----
    uint32_t preg[16][2][2];
    float ssum[2] = {0.f, 0.f};
#pragma unroll
    for (int kc = 0; kc < 16; kc++) {
        int krow = kc * 128 + wv * 16;
        s16x8 kf[2];
        if (WS) {
#pragma unroll
            for (int ks = 0; ks < 2; ks++)
                kf[ks] = *(const s16x8*)(kbfh + (size_t)(krow + m) * ND + ks * 32 + kb * 8);
        } else {
#pragma unroll
            for (int ks = 0; ks < 2; ks++) {
                const float* src = Kh + (size_t)(krow + m) * ND + ks * 32 + kb * 8;
                f32x4 a = *(const f32x4*)src;
                f32x4 c4 = *(const f32x4*)(src + 4);
                s16x8 f;
#pragma unroll
                for (int j = 0; j < 4; j++) {
                    f[j] = f2bf(a[j]);
                    f[4 + j] = f2bf(c4[j]);
                }
                kf[ks] = f;
            }
        }
        f32x4 c0 = {0.f, 0.f, 0.f, 0.f}, c1 = {0.f, 0.f, 0.f, 0.f};
        c0 = mfma16(kf[0], qf[0][0], c0);
        c0 = mfma16(kf[1], qf[0][1], c0);
        c1 = mfma16(kf[0], qf[1][0], c1);
        c1 = mfma16(kf[1], qf[1][1], c1);

        int kcol = krow + kb * 4;  // 4 consecutive score columns per lane
#pragma unroll
        for (int n = 0; n < 2; n++) {
            f32x4 c = n ? c1 : c0;
            int qglob = q0 + n * 16 + m;
            uint32_t keepbits;
            if (WS) {
                uint32_t word = bitsb[(size_t)qglob * (NS / 32) + (kcol >> 5)];
                keepbits = word >> (kcol & 31);
            } else {
                const int4 mi = *(const int4*)(maskb + (size_t)qglob * NS + kcol);
                keepbits = (uint32_t)(mi.x != 0) | ((uint32_t)(mi.y != 0) << 1) |
                           ((uint32_t)(mi.z != 0) << 2) | ((uint32_t)(mi.w != 0) << 3);
            }
            float p[4];
#pragma unroll
            for (int r = 0; r < 4; r++) {
                float s = c[r];
                bool keep = ((keepbits >> r) & 1u) && (s > 0.f);
                p[r] = keep ? s : 0.f;
            }
            ssum[n] += p[0] * p[0] + p[1] * p[1] + p[2] * p[2] + p[3] * p[3];
            preg[kc][n][0] = (uint32_t)(unsigned short)f2bf(p[0]) |
                             ((uint32_t)(unsigned short)f2bf(p[1]) << 16);
            preg[kc][n][1] = (uint32_t)(unsigned short)f2bf(p[2]) |
                             ((uint32_t)(unsigned short)f2bf(p[3]) << 16);
        }
    }

    // ---- row reduction -> 1/rms ----
    ssum[0] += __shfl_xor(ssum[0], 16);
    ssum[0] += __shfl_xor(ssum[0], 32);
    ssum[1] += __shfl_xor(ssum[1], 16);
    ssum[1] += __shfl_xor(ssum[1], 32);
    if (lane < 16) {
        red[wv * 32 + lane] = ssum[0];
        red[wv * 32 + 16 + lane] = ssum[1];
    }
    __syncthreads();
    if (tid < 32) {
        float s = 0.f;
#pragma unroll
        for (int i = 0; i < 8; i++) s += red[i * 32 + tid];
        rinv_sh[tid] = 1.0f / sqrtf(s * (1.0f / NS) + 1e-6f);
    }
    __syncthreads();

    // ---- Fused: per t = 2 k-chunks: stage P -> coalesced p_attn stream + PV ----
    f32x4 acc[4][2];
#pragma unroll
    for (int dt = 0; dt < 4; dt++)
#pragma unroll
        for (int n = 0; n < 2; n++) acc[dt][n] = (f32x4){0.f, 0.f, 0.f, 0.f};

#pragma unroll
    for (int t8 = 0; t8 < 8; t8++) {
        const int kc0 = 2 * t8, kc1 = 2 * t8 + 1;
        // (1) stage bf16 P: row q, col byte = h*256 + wv*32 + kb*8, XOR (q&7)<<4
#pragma unroll
        for (int n = 0; n < 2; n++) {
            int q = n * 16 + m;
#pragma unroll
            for (int h = 0; h < 2; h++) {
                int cb = (h * 256 + wv * 32 + kb * 8) ^ ((q & 7) << 4);
                uint2 u;
                u.x = preg[2 * t8 + h][n][0];
                u.y = preg[2 * t8 + h][n][1];
                *(uint2*)(stage + q * 512 + cb) = u;
            }
        }
        __syncthreads();
        // (2) coalesced stream: 16 threads/row, 2 halves -> 512B/row contiguous
        {
            int q = tid >> 4;
            float ri = rinv_sh[q];
#pragma unroll
            for (int half = 0; half < 2; half++) {
                int c = (tid & 15) + half * 16;  // 16B chunk index within row
                int byte = q * 512 + ((c * 16) ^ ((q & 7) << 4));
                s16x8 pv = *(const s16x8*)(stage + byte);
                int kcolg = t8 * 256 + c * 8;
                f32x4 w4a = *(const f32x4*)(wg + kcolg);
                f32x4 w4b = *(const f32x4*)(wg + kcolg + 4);
                f32x4 o1, o2;
#pragma unroll
                for (int j = 0; j < 4; j++) {
                    o1[j] = bf2f(pv[j]) * w4a[j] * ri;
                    o2[j] = bf2f(pv[4 + j]) * w4b[j] * ri;
                }
                float* dst = ph + (size_t)q * NS + kcolg;
                __builtin_nontemporal_store(o1, (f32x4*)dst);
                __builtin_nontemporal_store(o2, (f32x4*)(dst + 4));
            }
        }
        // (3) partial PV: VwT[d][k] fragments at the wave's own k-slot mapping
        s16x8 afr[4];
#pragma unroll
        for (int dt = 0; dt < 4; dt++) {
            if (WS) {
                const unsigned short* rb =
                    vwtg + ((size_t)bh * ND + dt * 16 + m) * NS + wv * 16 + kb * 4;
                uint2 l0 = *(const uint2*)(rb + kc0 * 128);
                uint2 l1 = *(const uint2*)(rb + kc1 * 128);
                u32x4 uu = {l0.x, l0.y, l1.x, l1.y};
                afr[dt] = __builtin_bit_cast(s16x8, uu);
            } else {
                s16x8 a;
#pragma unroll
                for (int j = 0; j < 4; j++) {
                    int k1 = kc0 * 128 + wv * 16 + kb * 4 + j;
                    int k2 = kc1 * 128 + wv * 16 + kb * 4 + j;
                    a[j] = f2bf(Vh[(size_t)k1 * ND + dt * 16 + m] * wg[k1]);
                    a[4 + j] = f2bf(Vh[(size_t)k2 * ND + dt * 16 + m] * wg[k2]);
                }
                afr[dt] = a;
            }
        }
#pragma unroll
        for (int n = 0; n < 2; n++) {
            u32x4 uu = {preg[kc0][n][0], preg[kc0][n][1], preg[kc1][n][0], preg[kc1][n][1]};
            s16x8 bfr = __builtin_bit_cast(s16x8, uu);
#pragma unroll
            for (int dt = 0; dt < 4; dt++) acc[dt][n] = mfma16(afr[dt], bfr, acc[dt][n]);
        }
        __syncthreads();  // staging reads done before next iter's writes
    }

    // ---- cross-wave out reduce in two 32-d halves through pO [8][32][36] ----
#pragma unroll
    for (int pr = 0; pr < 2; pr++) {
        __syncthreads();
#pragma unroll
        for (int dh = 0; dh < 2; dh++) {
            int dt = 2 * pr + dh;
#pragma unroll
            for (int n = 0; n < 2; n++) {
                int q = n * 16 + m;
                *(f32x4*)(pO + ((size_t)(wv * 32 + q)) * 36 + dh * 16 + kb * 4) = acc[dt][n];
            }
        }
        __syncthreads();
        if (tid < 256) {
            int q = tid >> 3, dl = (tid & 7) * 4;
            f32x4 s = {0.f, 0.f, 0.f, 0.f};
#pragma unroll
            for (int v = 0; v < 8; v++) {
                f32x4 x = *(const f32x4*)(pO + ((size_t)(v * 32 + q)) * 36 + dl);
                s[0] += x[0];
                s[1] += x[1];
                s[2] += x[2];
                s[3] += x[3];
            }
            float ri = rinv_sh[q];
            f32x4 o = {s[0] * ri, s[1] * ri, s[2] * ri, s[3] * ri};
            __builtin_nontemporal_store(o, (f32x4*)(outh + (size_t)(q0 + q) * ND + pr * 32 + dl));
        }
    }
}

extern "C" void kernel_launch(void* const* d_in, const int* in_sizes, int n_in,
                              void* d_out, int out_size, void* d_ws, size_t ws_size,
                              hipStream_t stream) {
    const float* Q = (const float*)d_in[0];
    const float* K = (const float*)d_in[1];
    const float* V = (const float*)d_in[2];
    const int* mask = (const int*)d_in[3];
    const float* w = (const float*)d_in[4];
    float* out = (float*)d_out;
    float* pattn = out + (size_t)NB * NH * NS * ND;

    const size_t bits_bytes = (size_t)NB * NS * (NS / 32) * sizeof(uint32_t);     // 1 MB
    const size_t vwt_bytes = (size_t)NB * NH * ND * NS * sizeof(unsigned short);  // 6.3 MB
    const size_t kbf_bytes = vwt_bytes;                                           // 6.3 MB
    const int nwg = NB * NH * (NS / 32);  // 1536
    const int smem = 36864 + 256 * 4 + 32 * 4;  // 38016 B

    if (ws_size >= bits_bytes + vwt_bytes + kbf_bytes) {
        uint32_t* bits = (uint32_t*)d_ws;
        unsigned short* vwt = (unsigned short*)((char*)d_ws + bits_bytes);
        unsigned short* kbf = (unsigned short*)((char*)d_ws + bits_bytes + vwt_bytes);
        kbits<<<(NB * NS * NS / 32) / 256, 256, 0, stream>>>(mask, bits);
        kvwt<<<NB * NH * (NS / 32), 256, 0, stream>>>(V, w, vwt);
        kcast<<<(NB * NH * NS * ND) / (256 * 8), 256, 0, stream>>>(K, kbf);
        hipFuncSetAttribute(reinterpret_cast<const void*>(&attn_main<true>),
                            hipFuncAttributeMaxDynamicSharedMemorySize, smem);
        attn_main<true><<<nwg, 512, smem, stream>>>(Q, K, V, mask, w, bits, vwt, kbf, out,
                                                    pattn);
    } else {
        hipFuncSetAttribute(reinterpret_cast<const void*>(&attn_main<false>),
                            hipFuncAttributeMaxDynamicSharedMemorySize, smem);
        attn_main<false><<<nwg, 512, smem, stream>>>(Q, K, V, mask, w, nullptr, nullptr, nullptr,
                                                     out, pattn);
    }
}